// Round 15
// baseline (128.678 us; speedup 1.0000x reference)
//
#include <hip/hip_runtime.h>
#include <stdint.h>

typedef short short8 __attribute__((ext_vector_type(8)));
typedef float f32x4 __attribute__((ext_vector_type(4)));

__device__ __forceinline__ unsigned short f2bf(float f) {
    union { float f; uint32_t u; } v; v.f = f;
    uint32_t u = v.u;
    u += 0x7FFFu + ((u >> 16) & 1u);   // round-to-nearest-even
    return (unsigned short)(u >> 16);
}

__device__ __forceinline__ uint32_t cvtpk(float lo, float hi) {
    uint32_t r;
    asm("v_cvt_pk_bf16_f32 %0, %1, %2" : "=v"(r) : "v"(lo), "v"(hi));
    return r;
}

__device__ __forceinline__ void gload_lds16(const void* g, void* l) {
    __builtin_amdgcn_global_load_lds(
        (const __attribute__((address_space(1))) void*)g,
        (__attribute__((address_space(3))) void*)l, 16, 0, 0);
}

// ---------------- fused prep: x->bf16 convert + W_attn / W_proj transposes ----------------
__device__ __forceinline__ void transpose_body(const float* __restrict__ in,
                                               unsigned short* __restrict__ out,
                                               int R, int Cc, int bx, int by,
                                               float (*tile)[33]) {
    int c0 = bx * 32, r0 = by * 32;
    int tr = threadIdx.x / 32, c = threadIdx.x % 32;
#pragma unroll
    for (int rr = tr; rr < 32; rr += 8)
        tile[rr][c] = in[(size_t)(r0 + rr) * Cc + c0 + c];
    __syncthreads();
#pragma unroll
    for (int rr = tr; rr < 32; rr += 8)
        out[(size_t)(c0 + rr) * R + r0 + c] = f2bf(tile[c][rr]);
}

__global__ void k_prep(const float* __restrict__ x, unsigned short* __restrict__ xb,
                       const float* __restrict__ Wa, unsigned short* __restrict__ WaT,
                       const float* __restrict__ Wp, unsigned short* __restrict__ WpT) {
    __shared__ float tile[32][33];
    const int blk = blockIdx.x;
    if (blk < 6144) {
        int i = blk * 256 + threadIdx.x;
        float4 f = ((const float4*)x)[i];
        ushort4 o;
        o.x = f2bf(f.x); o.y = f2bf(f.y); o.z = f2bf(f.z); o.w = f2bf(f.w);
        ((ushort4*)xb)[i] = o;
    } else if (blk < 6144 + 1728) {
        int id = blk - 6144;
        transpose_body(Wa, WaT, 768, 2304, id % 72, id / 72, tile);
    } else {
        int id = blk - 7872;
        transpose_body(Wp, WpT, 768, 768, id % 24, id / 24, tile);
    }
}

// ---------------- bf16 GEMM (R13 proven): C = A[M][K] * BT[N][K]^T + bias ----------------
// 128x128 tile, BK=64 in two 32-col LDS panels, 2 barriers per K-step.
// VSPLIT (gemm1): two-level XCD swizzle — 3 panels of 8m x 6n per XCD so the panel
// working set (2.75MB) fits per-XCD L2 (FETCH 38->24.7MB measured, dur 47.7->44.6).
// Also writes output columns n>=1536 (V heads) directly transposed to vt[96][64][1024].
template<bool F32OUT, bool VSPLIT>
__global__ __launch_bounds__(256, 3)
void k_gemm_bt(const unsigned short* __restrict__ A, const unsigned short* __restrict__ BT,
               const float* __restrict__ bias, void* __restrict__ Cout,
               unsigned short* __restrict__ Vt,
               int M, int N, int K) {
    __shared__ unsigned short As[2][128][32];
    __shared__ unsigned short Bs[2][128][32];
    const int nbx = gridDim.x;
    const int total = nbx * gridDim.y;
    const int id = blockIdx.y * nbx + blockIdx.x;
    int m_, n_;
    if (VSPLIT) {
        const int x = id & 7, j = id >> 3;
        const int panel = j / 48, jj = j % 48;
        m_ = x * 8 + (jj & 7);
        n_ = panel * 6 + (jj >> 3);
    } else {
        const int sw = (id & 7) * (total >> 3) + (id >> 3);
        m_ = sw / nbx;
        n_ = sw % nbx;
    }
    const int m0 = m_ * 128, n0 = n_ * 128;
    const int t = threadIdx.x;
    const int w = t >> 6, l = t & 63;
    const int wm = (w >> 1) * 64, wn = (w & 1) * 64;
    const int lr = l & 15, lg = l >> 4;
    const int srow = w * 32 + (l >> 2);
    const int scol = (l & 3) * 8;
    const unsigned short* pa = &A [(size_t)(m0 + srow) * K + scol];
    const unsigned short* pb = &BT[(size_t)(n0 + srow) * K + scol];

    f32x4 acc[4][4];
#pragma unroll
    for (int i = 0; i < 4; ++i)
#pragma unroll
        for (int j = 0; j < 4; ++j)
#pragma unroll
            for (int r = 0; r < 4; ++r) acc[i][j][r] = 0.0f;

    for (int k0 = 0; k0 < K; k0 += 64) {
        __syncthreads();
        gload_lds16(pa + k0,                        &As[0][w * 32][0]);
        gload_lds16(pa + (size_t)16 * K + k0,       &As[0][w * 32 + 16][0]);
        gload_lds16(pa + k0 + 32,                   &As[1][w * 32][0]);
        gload_lds16(pa + (size_t)16 * K + k0 + 32,  &As[1][w * 32 + 16][0]);
        gload_lds16(pb + k0,                        &Bs[0][w * 32][0]);
        gload_lds16(pb + (size_t)16 * K + k0,       &Bs[0][w * 32 + 16][0]);
        gload_lds16(pb + k0 + 32,                   &Bs[1][w * 32][0]);
        gload_lds16(pb + (size_t)16 * K + k0 + 32,  &Bs[1][w * 32 + 16][0]);
        __syncthreads();
#pragma unroll
        for (int p = 0; p < 2; ++p) {
            short8 af[4], bfv[4];
#pragma unroll
            for (int f = 0; f < 4; ++f) {
                af [f] = *(const short8*)&As[p][wm + f * 16 + lr][lg * 8];
                bfv[f] = *(const short8*)&Bs[p][wn + f * 16 + lr][lg * 8];
            }
#pragma unroll
            for (int mf = 0; mf < 4; ++mf)
#pragma unroll
                for (int nf = 0; nf < 4; ++nf)
                    acc[mf][nf] = __builtin_amdgcn_mfma_f32_16x16x32_bf16(af[mf], bfv[nf], acc[mf][nf], 0, 0, 0);
        }
    }

#pragma unroll
    for (int mf = 0; mf < 4; ++mf)
#pragma unroll
        for (int nf = 0; nf < 4; ++nf) {
            int n = n0 + wn + nf * 16 + lr;
            int mbase = m0 + wm + mf * 16 + lg * 4;
            float bv = bias[n];
            if (VSPLIT && n >= 1536) {
                int hh = (n - 1536) >> 6, dd = (n - 1536) & 63;
                int bb = mbase >> 10, tt = mbase & 1023;
                ushort4 o;
                o.x = f2bf(acc[mf][nf][0] + bv);
                o.y = f2bf(acc[mf][nf][1] + bv);
                o.z = f2bf(acc[mf][nf][2] + bv);
                o.w = f2bf(acc[mf][nf][3] + bv);
                *(ushort4*)&Vt[(((size_t)bb * 12 + hh) * 64 + dd) * 1024 + tt] = o;
            } else {
#pragma unroll
                for (int r = 0; r < 4; ++r) {
                    float v = acc[mf][nf][r] + bv;
                    if (F32OUT) ((float*)Cout)[(size_t)(mbase + r) * N + n] = v;
                    else ((unsigned short*)Cout)[(size_t)(mbase + r) * N + n] = f2bf(v);
                }
            }
        }
}

// ---------------- causal flash attention: complementary-pair q-tiles ----------------
// (R12 inner structure frozen; R15 changes the block->work mapping)
// Each block owns TWO 64-row q-tiles: a and 15-a (a in [0,8), bijective pairing).
// Group 0 = tile a (active while kti <= a), group 1 = tile 15-a (active all
// nkt = 16-a iterations). Causal compute per block = (a+1)+(16-a) = 17 group-tiles
// for EVERY block -> exact CU-level balance regardless of scheduler assignment
// (was 4qt+3 in {3..31}; stagger only softened it). The +3-per-32-slot stagger is
// kept on 'a' so co-resident blocks also mix staging-iteration counts (16-a in [9,16]).
__global__ __launch_bounds__(256, 3)
void k_attn(const unsigned short* __restrict__ qkv, const unsigned short* __restrict__ vt,
            unsigned short* __restrict__ y) {
    __shared__ unsigned short Ks[2][64][88];
    __shared__ unsigned short Vs[2][64][88];
    __shared__ unsigned short Ps[4][16][72];
    const int p = blockIdx.x;
    const int s = p >> 3;                          // slot within XCD (0..95)
    const int bh = (p & 7) * 12 + (s >> 3);
    const int a  = (s + 3 * (s >> 5)) & 7;         // low tile (64-row units), staggered
    const int qa = a, qb = 15 - a;                 // paired q-tiles
    const int b = bh / 12, h = bh % 12;
    const int t = threadIdx.x, w = t >> 6, l = t & 63, lr = l & 15, lg = l >> 4;

    const unsigned short* qbase = qkv + (size_t)b * 1024 * 2304 + h * 64;
    const unsigned short* kbase = qbase + 768;
    const unsigned short* vbase = vt + (size_t)bh * 64 * 1024;

    const int srow = t >> 2, scol = (t & 3) * 8;
    const unsigned short* kst = &kbase[(size_t)srow * 2304 + scol];
    const unsigned short* vst = &vbase[(size_t)srow * 1024 + scol];

    const int rowb0 = qa * 64 + w * 16;            // group row bases
    const int rowb1 = qb * 64 + w * 16;

    short8 qf[2][2];
#pragma unroll
    for (int g = 0; g < 2; ++g) {
        const unsigned short* qrow = &qbase[(size_t)((g ? rowb1 : rowb0) + lr) * 2304];
        qf[g][0] = *(const short8*)&qrow[lg * 8];
        qf[g][1] = *(const short8*)&qrow[32 + lg * 8];
    }

    float l_loc[2] = {0.0f, 0.0f};
    f32x4 o_acc[2][4];
#pragma unroll
    for (int g = 0; g < 2; ++g)
#pragma unroll
        for (int df = 0; df < 4; ++df)
#pragma unroll
            for (int r = 0; r < 4; ++r) o_acc[g][df][r] = 0.0f;

    {
        uint4 ka = *(const uint4*)(kst);
        uint4 kb = *(const uint4*)(kst + 32);
        uint4 va = *(const uint4*)(vst);
        uint4 vb = *(const uint4*)(vst + 32);
        *(uint4*)&Ks[0][srow][scol]      = ka;
        *(uint4*)&Ks[0][srow][scol + 32] = kb;
        *(uint4*)&Vs[0][srow][scol]      = va;
        *(uint4*)&Vs[0][srow][scol + 32] = vb;
    }
    __syncthreads();

    const int nkt = qb + 1;                        // 16 - a iterations
    int cur = 0;
    for (int kti = 0; kti < nkt; ++kti) {
        const int kt = kti * 64;
        const bool more = (kti + 1 < nkt);
        uint4 nka, nkb, nva, nvb;
        if (more) {
            const int kn = kt + 64;
            nka = *(const uint4*)(kst + (size_t)kn * 2304);
            nkb = *(const uint4*)(kst + (size_t)kn * 2304 + 32);
            nva = *(const uint4*)(vst + kn);
            nvb = *(const uint4*)(vst + kn + 32);
        }

        const bool act0 = (kti <= qa);             // group 0 active through its diagonal
        const bool dg0  = (kti == qa);
        const bool dg1  = (kti == qb);             // group 1 diagonal = last iteration

        f32x4 s0[4], s1[4];
        __builtin_amdgcn_s_setprio(1);
#pragma unroll
        for (int nf = 0; nf < 4; ++nf) {
            short8 kf0 = *(const short8*)&Ks[cur][nf * 16 + lr][lg * 8];
            short8 kf1 = *(const short8*)&Ks[cur][nf * 16 + lr][32 + lg * 8];
            f32x4 z0, z1;
#pragma unroll
            for (int r = 0; r < 4; ++r) { z0[r] = 0.0f; z1[r] = 0.0f; }
            if (act0 && (!dg0 || nf <= w)) {
                z0 = __builtin_amdgcn_mfma_f32_16x16x32_bf16(kf0, qf[0][0], z0, 0, 0, 0);
                z0 = __builtin_amdgcn_mfma_f32_16x16x32_bf16(kf1, qf[0][1], z0, 0, 0, 0);
            }
            if (!dg1 || nf <= w) {
                z1 = __builtin_amdgcn_mfma_f32_16x16x32_bf16(kf0, qf[1][0], z1, 0, 0, 0);
                z1 = __builtin_amdgcn_mfma_f32_16x16x32_bf16(kf1, qf[1][1], z1, 0, 0, 0);
            }
            s0[nf] = z0; s1[nf] = z1;
        }
        __builtin_amdgcn_s_setprio(0);

        short8 vf[4][2];
#pragma unroll
        for (int df = 0; df < 4; ++df) {
            vf[df][0] = *(const short8*)&Vs[cur][df * 16 + lr][lg * 8];
            vf[df][1] = *(const short8*)&Vs[cur][df * 16 + lr][32 + lg * 8];
        }

#pragma unroll
        for (int g = 0; g < 2; ++g) {
            if (g == 0 && !act0) continue;
            const bool diag = g ? dg1 : dg0;
            const int row = (g ? rowb1 : rowb0) + lr;
            float lsum = 0.0f;
#pragma unroll
            for (int nf = 0; nf < 4; ++nf) {
                float e[4];
#pragma unroll
                for (int r = 0; r < 4; ++r) {
                    int col = kt + nf * 16 + lg * 4 + r;
                    bool ok = !diag || (nf < w) || (col <= row);
                    float sv = g ? s1[nf][r] : s0[nf][r];
                    e[r] = ok ? __builtin_amdgcn_exp2f(fmaf(sv, 0.18033688f, -11.54156003f)) : 0.0f;
                    lsum += e[r];
                }
                uint2 u;
                u.x = cvtpk(e[0], e[1]);
                u.y = cvtpk(e[2], e[3]);
                *(uint2*)&Ps[w][lr][nf * 16 + lg * 4] = u;
            }
            l_loc[g] += lsum;
            short8 pf0 = *(const short8*)&Ps[w][lr][lg * 8];
            short8 pf1 = *(const short8*)&Ps[w][lr][32 + lg * 8];
            __builtin_amdgcn_s_setprio(1);
#pragma unroll
            for (int df = 0; df < 4; ++df) {
                o_acc[g][df] = __builtin_amdgcn_mfma_f32_16x16x32_bf16(pf0, vf[df][0], o_acc[g][df], 0, 0, 0);
                o_acc[g][df] = __builtin_amdgcn_mfma_f32_16x16x32_bf16(pf1, vf[df][1], o_acc[g][df], 0, 0, 0);
            }
            __builtin_amdgcn_s_setprio(0);
        }

        if (more) {
            *(uint4*)&Ks[cur ^ 1][srow][scol]      = nka;
            *(uint4*)&Ks[cur ^ 1][srow][scol + 32] = nkb;
            *(uint4*)&Vs[cur ^ 1][srow][scol]      = nva;
            *(uint4*)&Vs[cur ^ 1][srow][scol + 32] = nvb;
        }
        __syncthreads();
        cur ^= 1;
    }

#pragma unroll
    for (int g = 0; g < 2; ++g) {
        float dsum = l_loc[g];
        dsum += __shfl_xor(dsum, 16);
        dsum += __shfl_xor(dsum, 32);
#pragma unroll
        for (int r = 0; r < 4; ++r) {
            float inv = 1.0f / __shfl(dsum, lg * 4 + r);
            int rowy = (g ? rowb1 : rowb0) + lg * 4 + r;
#pragma unroll
            for (int df = 0; df < 4; ++df)
                y[((size_t)b * 1024 + rowy) * 768 + h * 64 + df * 16 + lr] = f2bf(o_acc[g][df][r] * inv);
        }
    }
}

extern "C" void kernel_launch(void* const* d_in, const int* in_sizes, int n_in,
                              void* d_out, int out_size, void* d_ws, size_t ws_size,
                              hipStream_t stream) {
    const float* x  = (const float*)d_in[0];
    const float* Wa = (const float*)d_in[1];
    const float* ba = (const float*)d_in[2];
    const float* Wp = (const float*)d_in[3];
    const float* bp = (const float*)d_in[4];
    float* out = (float*)d_out;

    char* ws = (char*)d_ws;
    unsigned short* qkv = (unsigned short*)ws;                          // 8192*2304*2 = 37,748,736
    unsigned short* xb  = (unsigned short*)(ws + 37748736);             // 8192*768*2  = 12,582,912
    unsigned short* WaT = (unsigned short*)(ws + 37748736 + 12582912);  // 2304*768*2  =  3,538,944
    unsigned short* WpT = (unsigned short*)(ws + 37748736 + 12582912 + 3538944); // 768*768*2
    unsigned short* y   = xb;    // reuse: xb dead after gemm1
    unsigned short* vtb = (unsigned short*)d_out;  // V^T scratch in d_out, overwritten by gemm2

    // 1) fused prep: x->bf16, W_attn transpose, W_proj transpose
    k_prep<<<8448, 256, 0, stream>>>(x, xb, Wa, WaT, Wp, WpT);
    // 2) qkv = xb @ WaT^T + b_attn (bf16); V heads written transposed straight to vtb
    k_gemm_bt<false, true><<<dim3(18, 64), 256, 0, stream>>>(xb, WaT, ba, qkv, vtb, 8192, 2304, 768);
    // 3) causal flash attention -> y (bf16)
    k_attn<<<768, 256, 0, stream>>>(qkv, vtb, y);
    // 4) out = y @ WpT^T + b_proj    (fp32 out)
    k_gemm_bt<true, false><<<dim3(6, 64), 256, 0, stream>>>(y, WpT, bp, out, nullptr, 8192, 768, 768);
}

// Round 16
// 116.139 us; speedup vs baseline: 1.1080x; 1.1080x over previous
//
#include <hip/hip_runtime.h>
#include <stdint.h>

typedef short short8 __attribute__((ext_vector_type(8)));
typedef float f32x4 __attribute__((ext_vector_type(4)));

__device__ __forceinline__ unsigned short f2bf(float f) {
    union { float f; uint32_t u; } v; v.f = f;
    uint32_t u = v.u;
    u += 0x7FFFu + ((u >> 16) & 1u);   // round-to-nearest-even
    return (unsigned short)(u >> 16);
}

__device__ __forceinline__ uint32_t cvtpk(float lo, float hi) {
    uint32_t r;
    asm("v_cvt_pk_bf16_f32 %0, %1, %2" : "=v"(r) : "v"(lo), "v"(hi));
    return r;
}

__device__ __forceinline__ void gload_lds16(const void* g, void* l) {
    __builtin_amdgcn_global_load_lds(
        (const __attribute__((address_space(1))) void*)g,
        (__attribute__((address_space(3))) void*)l, 16, 0, 0);
}

// ---------------- fused prep: x->bf16 convert + W_attn / W_proj transposes ----------------
__device__ __forceinline__ void transpose_body(const float* __restrict__ in,
                                               unsigned short* __restrict__ out,
                                               int R, int Cc, int bx, int by,
                                               float (*tile)[33]) {
    int c0 = bx * 32, r0 = by * 32;
    int tr = threadIdx.x / 32, c = threadIdx.x % 32;
#pragma unroll
    for (int rr = tr; rr < 32; rr += 8)
        tile[rr][c] = in[(size_t)(r0 + rr) * Cc + c0 + c];
    __syncthreads();
#pragma unroll
    for (int rr = tr; rr < 32; rr += 8)
        out[(size_t)(c0 + rr) * R + r0 + c] = f2bf(tile[c][rr]);
}

__global__ void k_prep(const float* __restrict__ x, unsigned short* __restrict__ xb,
                       const float* __restrict__ Wa, unsigned short* __restrict__ WaT,
                       const float* __restrict__ Wp, unsigned short* __restrict__ WpT) {
    __shared__ float tile[32][33];
    const int blk = blockIdx.x;
    if (blk < 6144) {
        int i = blk * 256 + threadIdx.x;
        float4 f = ((const float4*)x)[i];
        ushort4 o;
        o.x = f2bf(f.x); o.y = f2bf(f.y); o.z = f2bf(f.z); o.w = f2bf(f.w);
        ((ushort4*)xb)[i] = o;
    } else if (blk < 6144 + 1728) {
        int id = blk - 6144;
        transpose_body(Wa, WaT, 768, 2304, id % 72, id / 72, tile);
    } else {
        int id = blk - 7872;
        transpose_body(Wp, WpT, 768, 768, id % 24, id / 24, tile);
    }
}

// ---------------- bf16 GEMM (R13 proven): C = A[M][K] * BT[N][K]^T + bias ----------------
// 128x128 tile, BK=64 in two 32-col LDS panels, 2 barriers per K-step.
// VSPLIT (gemm1): two-level XCD swizzle — 3 panels of 8m x 6n per XCD so the panel
// working set (2.75MB) fits per-XCD L2 (FETCH 38->24.7MB measured, dur 47.7->44.6).
// Also writes output columns n>=1536 (V heads) directly transposed to vt[96][64][1024].
template<bool F32OUT, bool VSPLIT>
__global__ __launch_bounds__(256, 3)
void k_gemm_bt(const unsigned short* __restrict__ A, const unsigned short* __restrict__ BT,
               const float* __restrict__ bias, void* __restrict__ Cout,
               unsigned short* __restrict__ Vt,
               int M, int N, int K) {
    __shared__ unsigned short As[2][128][32];
    __shared__ unsigned short Bs[2][128][32];
    const int nbx = gridDim.x;
    const int total = nbx * gridDim.y;
    const int id = blockIdx.y * nbx + blockIdx.x;
    int m_, n_;
    if (VSPLIT) {
        const int x = id & 7, j = id >> 3;
        const int panel = j / 48, jj = j % 48;
        m_ = x * 8 + (jj & 7);
        n_ = panel * 6 + (jj >> 3);
    } else {
        const int sw = (id & 7) * (total >> 3) + (id >> 3);
        m_ = sw / nbx;
        n_ = sw % nbx;
    }
    const int m0 = m_ * 128, n0 = n_ * 128;
    const int t = threadIdx.x;
    const int w = t >> 6, l = t & 63;
    const int wm = (w >> 1) * 64, wn = (w & 1) * 64;
    const int lr = l & 15, lg = l >> 4;
    const int srow = w * 32 + (l >> 2);
    const int scol = (l & 3) * 8;
    const unsigned short* pa = &A [(size_t)(m0 + srow) * K + scol];
    const unsigned short* pb = &BT[(size_t)(n0 + srow) * K + scol];

    f32x4 acc[4][4];
#pragma unroll
    for (int i = 0; i < 4; ++i)
#pragma unroll
        for (int j = 0; j < 4; ++j)
#pragma unroll
            for (int r = 0; r < 4; ++r) acc[i][j][r] = 0.0f;

    for (int k0 = 0; k0 < K; k0 += 64) {
        __syncthreads();
        gload_lds16(pa + k0,                        &As[0][w * 32][0]);
        gload_lds16(pa + (size_t)16 * K + k0,       &As[0][w * 32 + 16][0]);
        gload_lds16(pa + k0 + 32,                   &As[1][w * 32][0]);
        gload_lds16(pa + (size_t)16 * K + k0 + 32,  &As[1][w * 32 + 16][0]);
        gload_lds16(pb + k0,                        &Bs[0][w * 32][0]);
        gload_lds16(pb + (size_t)16 * K + k0,       &Bs[0][w * 32 + 16][0]);
        gload_lds16(pb + k0 + 32,                   &Bs[1][w * 32][0]);
        gload_lds16(pb + (size_t)16 * K + k0 + 32,  &Bs[1][w * 32 + 16][0]);
        __syncthreads();
#pragma unroll
        for (int p = 0; p < 2; ++p) {
            short8 af[4], bfv[4];
#pragma unroll
            for (int f = 0; f < 4; ++f) {
                af [f] = *(const short8*)&As[p][wm + f * 16 + lr][lg * 8];
                bfv[f] = *(const short8*)&Bs[p][wn + f * 16 + lr][lg * 8];
            }
#pragma unroll
            for (int mf = 0; mf < 4; ++mf)
#pragma unroll
                for (int nf = 0; nf < 4; ++nf)
                    acc[mf][nf] = __builtin_amdgcn_mfma_f32_16x16x32_bf16(af[mf], bfv[nf], acc[mf][nf], 0, 0, 0);
        }
    }

#pragma unroll
    for (int mf = 0; mf < 4; ++mf)
#pragma unroll
        for (int nf = 0; nf < 4; ++nf) {
            int n = n0 + wn + nf * 16 + lr;
            int mbase = m0 + wm + mf * 16 + lg * 4;
            float bv = bias[n];
            if (VSPLIT && n >= 1536) {
                int hh = (n - 1536) >> 6, dd = (n - 1536) & 63;
                int bb = mbase >> 10, tt = mbase & 1023;
                ushort4 o;
                o.x = f2bf(acc[mf][nf][0] + bv);
                o.y = f2bf(acc[mf][nf][1] + bv);
                o.z = f2bf(acc[mf][nf][2] + bv);
                o.w = f2bf(acc[mf][nf][3] + bv);
                *(ushort4*)&Vt[(((size_t)bb * 12 + hh) * 64 + dd) * 1024 + tt] = o;
            } else {
#pragma unroll
                for (int r = 0; r < 4; ++r) {
                    float v = acc[mf][nf][r] + bv;
                    if (F32OUT) ((float*)Cout)[(size_t)(mbase + r) * N + n] = v;
                    else ((unsigned short*)Cout)[(size_t)(mbase + r) * N + n] = f2bf(v);
                }
            }
        }
}

// ---------------- causal flash attention: swapped-QK^T, in-register softmax ----------------
// (R14 inner structure EXACT revert — R15's pairing regressed: +28 VGPR, occupancy 26->14%,
//  staging iterations +39%. R16 changes ONLY the slot->qt permutation.)
// Slot->CU model (validated by R14's matched prediction): slots {i, i+32, i+64} co-reside
// on CU i. Per-stride permutations with CONSTANT triple sum:
//   P0(k)=k, P1(k)=(k+4)&7, P2(k)= k<4 ? 6-2k : 15-2k
//   -> qt1+qt2+qt3 = 10 or 11 for EVERY CU -> per-CU compute in {49,53} group-tile units
//   (R14 stagger: 37..65) and staging in {26,28} iterations. Each P is a permutation and
//   each bh's 8 slots lie in one stride -> (bh,qt) coverage bijective.
__global__ __launch_bounds__(256, 3)
void k_attn(const unsigned short* __restrict__ qkv, const unsigned short* __restrict__ vt,
            unsigned short* __restrict__ y) {
    __shared__ unsigned short Ks[2][64][88];
    __shared__ unsigned short Vs[2][64][88];
    __shared__ unsigned short Ps[4][16][72];
    const int p = blockIdx.x;
    const int s = p >> 3;                        // slot within XCD (0..95)
    const int bh = (p & 7) * 12 + (s >> 3);
    const int tier = s >> 5;                     // 32-slot stride index (0,1,2)
    const int kk = s & 7;
    const int qt = (tier == 0) ? kk
                 : (tier == 1) ? ((kk + 4) & 7)
                 : ((kk < 4) ? 6 - 2 * kk : 15 - 2 * kk);
    const int b = bh / 12, h = bh % 12;
    const int t = threadIdx.x, w = t >> 6, l = t & 63, lr = l & 15, lg = l >> 4;
    const int q0 = qt * 128;

    const unsigned short* qbase = qkv + (size_t)b * 1024 * 2304 + h * 64;
    const unsigned short* kbase = qbase + 768;
    const unsigned short* vbase = vt + (size_t)bh * 64 * 1024;

    const int srow = t >> 2, scol = (t & 3) * 8;
    const unsigned short* kst = &kbase[(size_t)srow * 2304 + scol];
    const unsigned short* vst = &vbase[(size_t)srow * 1024 + scol];

    short8 qf[2][2];
#pragma unroll
    for (int g = 0; g < 2; ++g) {
        const unsigned short* qrow = &qbase[(size_t)(q0 + g * 64 + w * 16 + lr) * 2304];
        qf[g][0] = *(const short8*)&qrow[lg * 8];
        qf[g][1] = *(const short8*)&qrow[32 + lg * 8];
    }

    float l_loc[2] = {0.0f, 0.0f};
    f32x4 o_acc[2][4];
#pragma unroll
    for (int g = 0; g < 2; ++g)
#pragma unroll
        for (int df = 0; df < 4; ++df)
#pragma unroll
            for (int r = 0; r < 4; ++r) o_acc[g][df][r] = 0.0f;

    {
        uint4 ka = *(const uint4*)(kst);
        uint4 kb = *(const uint4*)(kst + 32);
        uint4 va = *(const uint4*)(vst);
        uint4 vb = *(const uint4*)(vst + 32);
        *(uint4*)&Ks[0][srow][scol]      = ka;
        *(uint4*)&Ks[0][srow][scol + 32] = kb;
        *(uint4*)&Vs[0][srow][scol]      = va;
        *(uint4*)&Vs[0][srow][scol + 32] = vb;
    }
    __syncthreads();

    const int nkt = qt * 2 + 2;
    int cur = 0;
    for (int kti = 0; kti < nkt; ++kti) {
        const int kt = kti * 64;
        const bool more = (kti + 1 < nkt);
        uint4 nka, nkb, nva, nvb;
        if (more) {
            const int kn = kt + 64;
            nka = *(const uint4*)(kst + (size_t)kn * 2304);
            nkb = *(const uint4*)(kst + (size_t)kn * 2304 + 32);
            nva = *(const uint4*)(vst + kn);
            nvb = *(const uint4*)(vst + kn + 32);
        }

        const bool act0 = (kti < nkt - 1);
        const bool dg0  = (kti == nkt - 2);
        const bool dg1  = (kti == nkt - 1);

        f32x4 s0[4], s1[4];
        __builtin_amdgcn_s_setprio(1);
#pragma unroll
        for (int nf = 0; nf < 4; ++nf) {
            short8 kf0 = *(const short8*)&Ks[cur][nf * 16 + lr][lg * 8];
            short8 kf1 = *(const short8*)&Ks[cur][nf * 16 + lr][32 + lg * 8];
            f32x4 z0, z1;
#pragma unroll
            for (int r = 0; r < 4; ++r) { z0[r] = 0.0f; z1[r] = 0.0f; }
            if (act0 && (!dg0 || nf <= w)) {
                z0 = __builtin_amdgcn_mfma_f32_16x16x32_bf16(kf0, qf[0][0], z0, 0, 0, 0);
                z0 = __builtin_amdgcn_mfma_f32_16x16x32_bf16(kf1, qf[0][1], z0, 0, 0, 0);
            }
            if (!dg1 || nf <= w) {
                z1 = __builtin_amdgcn_mfma_f32_16x16x32_bf16(kf0, qf[1][0], z1, 0, 0, 0);
                z1 = __builtin_amdgcn_mfma_f32_16x16x32_bf16(kf1, qf[1][1], z1, 0, 0, 0);
            }
            s0[nf] = z0; s1[nf] = z1;
        }
        __builtin_amdgcn_s_setprio(0);

        short8 vf[4][2];
#pragma unroll
        for (int df = 0; df < 4; ++df) {
            vf[df][0] = *(const short8*)&Vs[cur][df * 16 + lr][lg * 8];
            vf[df][1] = *(const short8*)&Vs[cur][df * 16 + lr][32 + lg * 8];
        }

#pragma unroll
        for (int g = 0; g < 2; ++g) {
            if (g == 0 && !act0) continue;
            const bool diag = g ? dg1 : dg0;
            const int row = q0 + g * 64 + w * 16 + lr;
            float lsum = 0.0f;
#pragma unroll
            for (int nf = 0; nf < 4; ++nf) {
                float e[4];
#pragma unroll
                for (int r = 0; r < 4; ++r) {
                    int col = kt + nf * 16 + lg * 4 + r;
                    bool ok = !diag || (nf < w) || (col <= row);
                    float sv = g ? s1[nf][r] : s0[nf][r];
                    e[r] = ok ? __builtin_amdgcn_exp2f(fmaf(sv, 0.18033688f, -11.54156003f)) : 0.0f;
                    lsum += e[r];
                }
                uint2 u;
                u.x = cvtpk(e[0], e[1]);
                u.y = cvtpk(e[2], e[3]);
                *(uint2*)&Ps[w][lr][nf * 16 + lg * 4] = u;
            }
            l_loc[g] += lsum;
            short8 pf0 = *(const short8*)&Ps[w][lr][lg * 8];
            short8 pf1 = *(const short8*)&Ps[w][lr][32 + lg * 8];
            __builtin_amdgcn_s_setprio(1);
#pragma unroll
            for (int df = 0; df < 4; ++df) {
                o_acc[g][df] = __builtin_amdgcn_mfma_f32_16x16x32_bf16(pf0, vf[df][0], o_acc[g][df], 0, 0, 0);
                o_acc[g][df] = __builtin_amdgcn_mfma_f32_16x16x32_bf16(pf1, vf[df][1], o_acc[g][df], 0, 0, 0);
            }
            __builtin_amdgcn_s_setprio(0);
        }

        if (more) {
            *(uint4*)&Ks[cur ^ 1][srow][scol]      = nka;
            *(uint4*)&Ks[cur ^ 1][srow][scol + 32] = nkb;
            *(uint4*)&Vs[cur ^ 1][srow][scol]      = nva;
            *(uint4*)&Vs[cur ^ 1][srow][scol + 32] = nvb;
        }
        __syncthreads();
        cur ^= 1;
    }

#pragma unroll
    for (int g = 0; g < 2; ++g) {
        float dsum = l_loc[g];
        dsum += __shfl_xor(dsum, 16);
        dsum += __shfl_xor(dsum, 32);
#pragma unroll
        for (int r = 0; r < 4; ++r) {
            float inv = 1.0f / __shfl(dsum, lg * 4 + r);
            int rowy = q0 + g * 64 + w * 16 + lg * 4 + r;
#pragma unroll
            for (int df = 0; df < 4; ++df)
                y[((size_t)b * 1024 + rowy) * 768 + h * 64 + df * 16 + lr] = f2bf(o_acc[g][df][r] * inv);
        }
    }
}

extern "C" void kernel_launch(void* const* d_in, const int* in_sizes, int n_in,
                              void* d_out, int out_size, void* d_ws, size_t ws_size,
                              hipStream_t stream) {
    const float* x  = (const float*)d_in[0];
    const float* Wa = (const float*)d_in[1];
    const float* ba = (const float*)d_in[2];
    const float* Wp = (const float*)d_in[3];
    const float* bp = (const float*)d_in[4];
    float* out = (float*)d_out;

    char* ws = (char*)d_ws;
    unsigned short* qkv = (unsigned short*)ws;                          // 8192*2304*2 = 37,748,736
    unsigned short* xb  = (unsigned short*)(ws + 37748736);             // 8192*768*2  = 12,582,912
    unsigned short* WaT = (unsigned short*)(ws + 37748736 + 12582912);  // 2304*768*2  =  3,538,944
    unsigned short* WpT = (unsigned short*)(ws + 37748736 + 12582912 + 3538944); // 768*768*2
    unsigned short* y   = xb;    // reuse: xb dead after gemm1
    unsigned short* vtb = (unsigned short*)d_out;  // V^T scratch in d_out, overwritten by gemm2

    // 1) fused prep: x->bf16, W_attn transpose, W_proj transpose
    k_prep<<<8448, 256, 0, stream>>>(x, xb, Wa, WaT, Wp, WpT);
    // 2) qkv = xb @ WaT^T + b_attn (bf16); V heads written transposed straight to vtb
    k_gemm_bt<false, true><<<dim3(18, 64), 256, 0, stream>>>(xb, WaT, ba, qkv, vtb, 8192, 2304, 768);
    // 3) causal flash attention -> y (bf16)
    k_attn<<<768, 256, 0, stream>>>(qkv, vtb, y);
    // 4) out = y @ WpT^T + b_proj    (fp32 out)
    k_gemm_bt<true, false><<<dim3(6, 64), 256, 0, stream>>>(y, WpT, bp, out, nullptr, 8192, 768, 768);
}

// Round 17
// 106.827 us; speedup vs baseline: 1.2045x; 1.0872x over previous
//
#include <hip/hip_runtime.h>
#include <stdint.h>

typedef short short8 __attribute__((ext_vector_type(8)));
typedef float f32x4 __attribute__((ext_vector_type(4)));

__device__ __forceinline__ unsigned short f2bf(float f) {
    union { float f; uint32_t u; } v; v.f = f;
    uint32_t u = v.u;
    u += 0x7FFFu + ((u >> 16) & 1u);   // round-to-nearest-even
    return (unsigned short)(u >> 16);
}

__device__ __forceinline__ uint32_t cvtpk(float lo, float hi) {
    uint32_t r;
    asm("v_cvt_pk_bf16_f32 %0, %1, %2" : "=v"(r) : "v"(lo), "v"(hi));
    return r;
}

__device__ __forceinline__ void gload_lds16(const void* g, void* l) {
    __builtin_amdgcn_global_load_lds(
        (const __attribute__((address_space(1))) void*)g,
        (__attribute__((address_space(3))) void*)l, 16, 0, 0);
}

// ---------------- fused prep: x->bf16 convert + W_attn / W_proj transposes ----------------
__device__ __forceinline__ void transpose_body(const float* __restrict__ in,
                                               unsigned short* __restrict__ out,
                                               int R, int Cc, int bx, int by,
                                               float (*tile)[33]) {
    int c0 = bx * 32, r0 = by * 32;
    int tr = threadIdx.x / 32, c = threadIdx.x % 32;
#pragma unroll
    for (int rr = tr; rr < 32; rr += 8)
        tile[rr][c] = in[(size_t)(r0 + rr) * Cc + c0 + c];
    __syncthreads();
#pragma unroll
    for (int rr = tr; rr < 32; rr += 8)
        out[(size_t)(c0 + rr) * R + r0 + c] = f2bf(tile[c][rr]);
}

__global__ void k_prep(const float* __restrict__ x, unsigned short* __restrict__ xb,
                       const float* __restrict__ Wa, unsigned short* __restrict__ WaT,
                       const float* __restrict__ Wp, unsigned short* __restrict__ WpT) {
    __shared__ float tile[32][33];
    const int blk = blockIdx.x;
    if (blk < 6144) {
        int i = blk * 256 + threadIdx.x;
        float4 f = ((const float4*)x)[i];
        ushort4 o;
        o.x = f2bf(f.x); o.y = f2bf(f.y); o.z = f2bf(f.z); o.w = f2bf(f.w);
        ((ushort4*)xb)[i] = o;
    } else if (blk < 6144 + 1728) {
        int id = blk - 6144;
        transpose_body(Wa, WaT, 768, 2304, id % 72, id / 72, tile);
    } else {
        int id = blk - 7872;
        transpose_body(Wp, WpT, 768, 768, id % 24, id / 24, tile);
    }
}

// ---------------- bf16 GEMM: C = A[M][K] * BT[N][K]^T + bias ----------------
// 128 x (NFRAG*32) tile, BK=64 in two 32-col LDS panels, 2 barriers per K-step.
// NFRAG=4 (gemm1): 128x128 tile; two-level XCD panel swizzle (R13: FETCH 38->24.7MB).
// NFRAG=2 (gemm2): 128x64 tile -> grid 12x64 = 768 = EXACTLY 3 blocks/CU (was 384 =
//   1.5/CU: half the CUs had double work and set the makespan). acc halves to 4x2 frags.
// VSPLIT (gemm1 only): output columns n>=1536 (V heads) written directly in
// transposed vt[96][64][1024] layout.
template<bool F32OUT, bool VSPLIT, int NFRAG>
__global__ __launch_bounds__(256, 3)
void k_gemm_bt(const unsigned short* __restrict__ A, const unsigned short* __restrict__ BT,
               const float* __restrict__ bias, void* __restrict__ Cout,
               unsigned short* __restrict__ Vt,
               int M, int N, int K) {
    __shared__ unsigned short As[2][128][32];
    __shared__ unsigned short Bs[2][NFRAG * 32][32];
    const int nbx = gridDim.x;
    const int total = nbx * gridDim.y;
    const int id = blockIdx.y * nbx + blockIdx.x;
    int m_, n_;
    if (VSPLIT) {
        const int x = id & 7, j = id >> 3;
        const int panel = j / 48, jj = j % 48;
        m_ = x * 8 + (jj & 7);
        n_ = panel * 6 + (jj >> 3);
    } else {
        const int sw = (id & 7) * (total >> 3) + (id >> 3);
        m_ = sw / nbx;
        n_ = sw % nbx;
    }
    const int m0 = m_ * 128, n0 = n_ * (NFRAG * 32);
    const int t = threadIdx.x;
    const int w = t >> 6, l = t & 63;
    const int wm = (w >> 1) * 64, wn = (w & 1) * (NFRAG * 16);
    const int lr = l & 15, lg = l >> 4;
    const int srow = w * 32 + (l >> 2);                       // A staging rows
    const int srowB = (NFRAG == 4) ? srow : (w * 16 + (l >> 2)); // B staging rows
    const int scol = (l & 3) * 8;
    const unsigned short* pa = &A [(size_t)(m0 + srow)  * K + scol];
    const unsigned short* pb = &BT[(size_t)(n0 + srowB) * K + scol];

    f32x4 acc[4][NFRAG];
#pragma unroll
    for (int i = 0; i < 4; ++i)
#pragma unroll
        for (int j = 0; j < NFRAG; ++j)
#pragma unroll
            for (int r = 0; r < 4; ++r) acc[i][j][r] = 0.0f;

    for (int k0 = 0; k0 < K; k0 += 64) {
        __syncthreads();
        gload_lds16(pa + k0,                        &As[0][w * 32][0]);
        gload_lds16(pa + (size_t)16 * K + k0,       &As[0][w * 32 + 16][0]);
        gload_lds16(pa + k0 + 32,                   &As[1][w * 32][0]);
        gload_lds16(pa + (size_t)16 * K + k0 + 32,  &As[1][w * 32 + 16][0]);
        if (NFRAG == 4) {
            gload_lds16(pb + k0,                        &Bs[0][w * 32][0]);
            gload_lds16(pb + (size_t)16 * K + k0,       &Bs[0][w * 32 + 16][0]);
            gload_lds16(pb + k0 + 32,                   &Bs[1][w * 32][0]);
            gload_lds16(pb + (size_t)16 * K + k0 + 32,  &Bs[1][w * 32 + 16][0]);
        } else {
            gload_lds16(pb + k0,                        &Bs[0][w * 16][0]);
            gload_lds16(pb + k0 + 32,                   &Bs[1][w * 16][0]);
        }
        __syncthreads();
#pragma unroll
        for (int p = 0; p < 2; ++p) {
            short8 af[4], bfv[NFRAG];
#pragma unroll
            for (int f = 0; f < 4; ++f)
                af[f] = *(const short8*)&As[p][wm + f * 16 + lr][lg * 8];
#pragma unroll
            for (int f = 0; f < NFRAG; ++f)
                bfv[f] = *(const short8*)&Bs[p][wn + f * 16 + lr][lg * 8];
#pragma unroll
            for (int mf = 0; mf < 4; ++mf)
#pragma unroll
                for (int nf = 0; nf < NFRAG; ++nf)
                    acc[mf][nf] = __builtin_amdgcn_mfma_f32_16x16x32_bf16(af[mf], bfv[nf], acc[mf][nf], 0, 0, 0);
        }
    }

#pragma unroll
    for (int mf = 0; mf < 4; ++mf)
#pragma unroll
        for (int nf = 0; nf < NFRAG; ++nf) {
            int n = n0 + wn + nf * 16 + lr;
            int mbase = m0 + wm + mf * 16 + lg * 4;
            float bv = bias[n];
            if (VSPLIT && n >= 1536) {
                int hh = (n - 1536) >> 6, dd = (n - 1536) & 63;
                int bb = mbase >> 10, tt = mbase & 1023;
                ushort4 o;
                o.x = f2bf(acc[mf][nf][0] + bv);
                o.y = f2bf(acc[mf][nf][1] + bv);
                o.z = f2bf(acc[mf][nf][2] + bv);
                o.w = f2bf(acc[mf][nf][3] + bv);
                *(ushort4*)&Vt[(((size_t)bb * 12 + hh) * 64 + dd) * 1024 + tt] = o;
            } else {
#pragma unroll
                for (int r = 0; r < 4; ++r) {
                    float v = acc[mf][nf][r] + bv;
                    if (F32OUT) ((float*)Cout)[(size_t)(mbase + r) * N + n] = v;
                    else ((unsigned short*)Cout)[(size_t)(mbase + r) * N + n] = f2bf(v);
                }
            }
        }
}

// ---------------- causal flash attention: swapped-QK^T, in-register softmax ----------------
// EXACT R14 state (benched 108.0 total, attn ~34us): +3-per-32-slot qt stagger.
// R15 (complementary pairing) and R16 (constant-sum permutation) both regressed —
// the slot->CU model is only reliable enough for the R14 dispersion heuristic.
__global__ __launch_bounds__(256, 3)
void k_attn(const unsigned short* __restrict__ qkv, const unsigned short* __restrict__ vt,
            unsigned short* __restrict__ y) {
    __shared__ unsigned short Ks[2][64][88];
    __shared__ unsigned short Vs[2][64][88];
    __shared__ unsigned short Ps[4][16][72];
    const int p = blockIdx.x;
    const int s = p >> 3;                        // slot within XCD (0..95)
    const int bh = (p & 7) * 12 + (s >> 3);
    const int qt = 7 - ((s + 3 * (s >> 5)) & 7); // R14 stagger (measured best)
    const int b = bh / 12, h = bh % 12;
    const int t = threadIdx.x, w = t >> 6, l = t & 63, lr = l & 15, lg = l >> 4;
    const int q0 = qt * 128;

    const unsigned short* qbase = qkv + (size_t)b * 1024 * 2304 + h * 64;
    const unsigned short* kbase = qbase + 768;
    const unsigned short* vbase = vt + (size_t)bh * 64 * 1024;

    const int srow = t >> 2, scol = (t & 3) * 8;
    const unsigned short* kst = &kbase[(size_t)srow * 2304 + scol];
    const unsigned short* vst = &vbase[(size_t)srow * 1024 + scol];

    short8 qf[2][2];
#pragma unroll
    for (int g = 0; g < 2; ++g) {
        const unsigned short* qrow = &qbase[(size_t)(q0 + g * 64 + w * 16 + lr) * 2304];
        qf[g][0] = *(const short8*)&qrow[lg * 8];
        qf[g][1] = *(const short8*)&qrow[32 + lg * 8];
    }

    float l_loc[2] = {0.0f, 0.0f};
    f32x4 o_acc[2][4];
#pragma unroll
    for (int g = 0; g < 2; ++g)
#pragma unroll
        for (int df = 0; df < 4; ++df)
#pragma unroll
            for (int r = 0; r < 4; ++r) o_acc[g][df][r] = 0.0f;

    {
        uint4 ka = *(const uint4*)(kst);
        uint4 kb = *(const uint4*)(kst + 32);
        uint4 va = *(const uint4*)(vst);
        uint4 vb = *(const uint4*)(vst + 32);
        *(uint4*)&Ks[0][srow][scol]      = ka;
        *(uint4*)&Ks[0][srow][scol + 32] = kb;
        *(uint4*)&Vs[0][srow][scol]      = va;
        *(uint4*)&Vs[0][srow][scol + 32] = vb;
    }
    __syncthreads();

    const int nkt = qt * 2 + 2;
    int cur = 0;
    for (int kti = 0; kti < nkt; ++kti) {
        const int kt = kti * 64;
        const bool more = (kti + 1 < nkt);
        uint4 nka, nkb, nva, nvb;
        if (more) {
            const int kn = kt + 64;
            nka = *(const uint4*)(kst + (size_t)kn * 2304);
            nkb = *(const uint4*)(kst + (size_t)kn * 2304 + 32);
            nva = *(const uint4*)(vst + kn);
            nvb = *(const uint4*)(vst + kn + 32);
        }

        const bool act0 = (kti < nkt - 1);
        const bool dg0  = (kti == nkt - 2);
        const bool dg1  = (kti == nkt - 1);

        f32x4 s0[4], s1[4];
        __builtin_amdgcn_s_setprio(1);
#pragma unroll
        for (int nf = 0; nf < 4; ++nf) {
            short8 kf0 = *(const short8*)&Ks[cur][nf * 16 + lr][lg * 8];
            short8 kf1 = *(const short8*)&Ks[cur][nf * 16 + lr][32 + lg * 8];
            f32x4 z0, z1;
#pragma unroll
            for (int r = 0; r < 4; ++r) { z0[r] = 0.0f; z1[r] = 0.0f; }
            if (act0 && (!dg0 || nf <= w)) {
                z0 = __builtin_amdgcn_mfma_f32_16x16x32_bf16(kf0, qf[0][0], z0, 0, 0, 0);
                z0 = __builtin_amdgcn_mfma_f32_16x16x32_bf16(kf1, qf[0][1], z0, 0, 0, 0);
            }
            if (!dg1 || nf <= w) {
                z1 = __builtin_amdgcn_mfma_f32_16x16x32_bf16(kf0, qf[1][0], z1, 0, 0, 0);
                z1 = __builtin_amdgcn_mfma_f32_16x16x32_bf16(kf1, qf[1][1], z1, 0, 0, 0);
            }
            s0[nf] = z0; s1[nf] = z1;
        }
        __builtin_amdgcn_s_setprio(0);

        short8 vf[4][2];
#pragma unroll
        for (int df = 0; df < 4; ++df) {
            vf[df][0] = *(const short8*)&Vs[cur][df * 16 + lr][lg * 8];
            vf[df][1] = *(const short8*)&Vs[cur][df * 16 + lr][32 + lg * 8];
        }

#pragma unroll
        for (int g = 0; g < 2; ++g) {
            if (g == 0 && !act0) continue;
            const bool diag = g ? dg1 : dg0;
            const int row = q0 + g * 64 + w * 16 + lr;
            float lsum = 0.0f;
#pragma unroll
            for (int nf = 0; nf < 4; ++nf) {
                float e[4];
#pragma unroll
                for (int r = 0; r < 4; ++r) {
                    int col = kt + nf * 16 + lg * 4 + r;
                    bool ok = !diag || (nf < w) || (col <= row);
                    float sv = g ? s1[nf][r] : s0[nf][r];
                    e[r] = ok ? __builtin_amdgcn_exp2f(fmaf(sv, 0.18033688f, -11.54156003f)) : 0.0f;
                    lsum += e[r];
                }
                uint2 u;
                u.x = cvtpk(e[0], e[1]);
                u.y = cvtpk(e[2], e[3]);
                *(uint2*)&Ps[w][lr][nf * 16 + lg * 4] = u;
            }
            l_loc[g] += lsum;
            short8 pf0 = *(const short8*)&Ps[w][lr][lg * 8];
            short8 pf1 = *(const short8*)&Ps[w][lr][32 + lg * 8];
            __builtin_amdgcn_s_setprio(1);
#pragma unroll
            for (int df = 0; df < 4; ++df) {
                o_acc[g][df] = __builtin_amdgcn_mfma_f32_16x16x32_bf16(pf0, vf[df][0], o_acc[g][df], 0, 0, 0);
                o_acc[g][df] = __builtin_amdgcn_mfma_f32_16x16x32_bf16(pf1, vf[df][1], o_acc[g][df], 0, 0, 0);
            }
            __builtin_amdgcn_s_setprio(0);
        }

        if (more) {
            *(uint4*)&Ks[cur ^ 1][srow][scol]      = nka;
            *(uint4*)&Ks[cur ^ 1][srow][scol + 32] = nkb;
            *(uint4*)&Vs[cur ^ 1][srow][scol]      = nva;
            *(uint4*)&Vs[cur ^ 1][srow][scol + 32] = nvb;
        }
        __syncthreads();
        cur ^= 1;
    }

#pragma unroll
    for (int g = 0; g < 2; ++g) {
        float dsum = l_loc[g];
        dsum += __shfl_xor(dsum, 16);
        dsum += __shfl_xor(dsum, 32);
#pragma unroll
        for (int r = 0; r < 4; ++r) {
            float inv = 1.0f / __shfl(dsum, lg * 4 + r);
            int rowy = q0 + g * 64 + w * 16 + lg * 4 + r;
#pragma unroll
            for (int df = 0; df < 4; ++df)
                y[((size_t)b * 1024 + rowy) * 768 + h * 64 + df * 16 + lr] = f2bf(o_acc[g][df][r] * inv);
        }
    }
}

extern "C" void kernel_launch(void* const* d_in, const int* in_sizes, int n_in,
                              void* d_out, int out_size, void* d_ws, size_t ws_size,
                              hipStream_t stream) {
    const float* x  = (const float*)d_in[0];
    const float* Wa = (const float*)d_in[1];
    const float* ba = (const float*)d_in[2];
    const float* Wp = (const float*)d_in[3];
    const float* bp = (const float*)d_in[4];
    float* out = (float*)d_out;

    char* ws = (char*)d_ws;
    unsigned short* qkv = (unsigned short*)ws;                          // 8192*2304*2 = 37,748,736
    unsigned short* xb  = (unsigned short*)(ws + 37748736);             // 8192*768*2  = 12,582,912
    unsigned short* WaT = (unsigned short*)(ws + 37748736 + 12582912);  // 2304*768*2  =  3,538,944
    unsigned short* WpT = (unsigned short*)(ws + 37748736 + 12582912 + 3538944); // 768*768*2
    unsigned short* y   = xb;    // reuse: xb dead after gemm1
    unsigned short* vtb = (unsigned short*)d_out;  // V^T scratch in d_out, overwritten by gemm2

    // 1) fused prep: x->bf16, W_attn transpose, W_proj transpose
    k_prep<<<8448, 256, 0, stream>>>(x, xb, Wa, WaT, Wp, WpT);
    // 2) qkv = xb @ WaT^T + b_attn (bf16); V heads written transposed straight to vtb
    k_gemm_bt<false, true, 4><<<dim3(18, 64), 256, 0, stream>>>(xb, WaT, ba, qkv, vtb, 8192, 2304, 768);
    // 3) causal flash attention -> y (bf16)
    k_attn<<<768, 256, 0, stream>>>(qkv, vtb, y);
    // 4) out = y @ WpT^T + b_proj (fp32); 128x64 tiles -> 768 blocks = 3.0/CU exact
    k_gemm_bt<true, false, 2><<<dim3(12, 64), 256, 0, stream>>>(y, WpT, bp, out, nullptr, 8192, 768, 768);
}

// Round 18
// 103.154 us; speedup vs baseline: 1.2474x; 1.0356x over previous
//
#include <hip/hip_runtime.h>
#include <stdint.h>

typedef short short8 __attribute__((ext_vector_type(8)));
typedef float f32x4 __attribute__((ext_vector_type(4)));

__device__ __forceinline__ unsigned short f2bf(float f) {
    union { float f; uint32_t u; } v; v.f = f;
    uint32_t u = v.u;
    u += 0x7FFFu + ((u >> 16) & 1u);   // round-to-nearest-even
    return (unsigned short)(u >> 16);
}

__device__ __forceinline__ uint32_t cvtpk(float lo, float hi) {
    uint32_t r;
    asm("v_cvt_pk_bf16_f32 %0, %1, %2" : "=v"(r) : "v"(lo), "v"(hi));
    return r;
}

__device__ __forceinline__ void gload_lds16(const void* g, void* l) {
    __builtin_amdgcn_global_load_lds(
        (const __attribute__((address_space(1))) void*)g,
        (__attribute__((address_space(3))) void*)l, 16, 0, 0);
}

// ---------------- fused prep: x->bf16 convert + W_attn / W_proj transposes ----------------
__device__ __forceinline__ void transpose_body(const float* __restrict__ in,
                                               unsigned short* __restrict__ out,
                                               int R, int Cc, int bx, int by,
                                               float (*tile)[33]) {
    int c0 = bx * 32, r0 = by * 32;
    int tr = threadIdx.x / 32, c = threadIdx.x % 32;
#pragma unroll
    for (int rr = tr; rr < 32; rr += 8)
        tile[rr][c] = in[(size_t)(r0 + rr) * Cc + c0 + c];
    __syncthreads();
#pragma unroll
    for (int rr = tr; rr < 32; rr += 8)
        out[(size_t)(c0 + rr) * R + r0 + c] = f2bf(tile[c][rr]);
}

__global__ void k_prep(const float* __restrict__ x, unsigned short* __restrict__ xb,
                       const float* __restrict__ Wa, unsigned short* __restrict__ WaT,
                       const float* __restrict__ Wp, unsigned short* __restrict__ WpT) {
    __shared__ float tile[32][33];
    const int blk = blockIdx.x;
    if (blk < 6144) {
        int i = blk * 256 + threadIdx.x;
        float4 f = ((const float4*)x)[i];
        ushort4 o;
        o.x = f2bf(f.x); o.y = f2bf(f.y); o.z = f2bf(f.z); o.w = f2bf(f.w);
        ((ushort4*)xb)[i] = o;
    } else if (blk < 6144 + 1728) {
        int id = blk - 6144;
        transpose_body(Wa, WaT, 768, 2304, id % 72, id / 72, tile);
    } else {
        int id = blk - 7872;
        transpose_body(Wp, WpT, 768, 768, id % 24, id / 24, tile);
    }
}

// ---------------- bf16 GEMM (R17 frozen): C = A[M][K] * BT[N][K]^T + bias ----------------
// 128 x (NFRAG*32) tile, BK=64 in two 32-col LDS panels, 2 barriers per K-step.
// NFRAG=4 (gemm1): 128x128; two-level XCD panel swizzle (FETCH 38->24.7MB measured).
// NFRAG=2 (gemm2): 128x64 -> grid 12x64 = 768 = exactly 3 blocks/CU.
// VSPLIT (gemm1 only): V-head columns written directly transposed to vt[96][64][1024].
template<bool F32OUT, bool VSPLIT, int NFRAG>
__global__ __launch_bounds__(256, 3)
void k_gemm_bt(const unsigned short* __restrict__ A, const unsigned short* __restrict__ BT,
               const float* __restrict__ bias, void* __restrict__ Cout,
               unsigned short* __restrict__ Vt,
               int M, int N, int K) {
    __shared__ unsigned short As[2][128][32];
    __shared__ unsigned short Bs[2][NFRAG * 32][32];
    const int nbx = gridDim.x;
    const int total = nbx * gridDim.y;
    const int id = blockIdx.y * nbx + blockIdx.x;
    int m_, n_;
    if (VSPLIT) {
        const int x = id & 7, j = id >> 3;
        const int panel = j / 48, jj = j % 48;
        m_ = x * 8 + (jj & 7);
        n_ = panel * 6 + (jj >> 3);
    } else {
        const int sw = (id & 7) * (total >> 3) + (id >> 3);
        m_ = sw / nbx;
        n_ = sw % nbx;
    }
    const int m0 = m_ * 128, n0 = n_ * (NFRAG * 32);
    const int t = threadIdx.x;
    const int w = t >> 6, l = t & 63;
    const int wm = (w >> 1) * 64, wn = (w & 1) * (NFRAG * 16);
    const int lr = l & 15, lg = l >> 4;
    const int srow = w * 32 + (l >> 2);
    const int srowB = (NFRAG == 4) ? srow : (w * 16 + (l >> 2));
    const int scol = (l & 3) * 8;
    const unsigned short* pa = &A [(size_t)(m0 + srow)  * K + scol];
    const unsigned short* pb = &BT[(size_t)(n0 + srowB) * K + scol];

    f32x4 acc[4][NFRAG];
#pragma unroll
    for (int i = 0; i < 4; ++i)
#pragma unroll
        for (int j = 0; j < NFRAG; ++j)
#pragma unroll
            for (int r = 0; r < 4; ++r) acc[i][j][r] = 0.0f;

    for (int k0 = 0; k0 < K; k0 += 64) {
        __syncthreads();
        gload_lds16(pa + k0,                        &As[0][w * 32][0]);
        gload_lds16(pa + (size_t)16 * K + k0,       &As[0][w * 32 + 16][0]);
        gload_lds16(pa + k0 + 32,                   &As[1][w * 32][0]);
        gload_lds16(pa + (size_t)16 * K + k0 + 32,  &As[1][w * 32 + 16][0]);
        if (NFRAG == 4) {
            gload_lds16(pb + k0,                        &Bs[0][w * 32][0]);
            gload_lds16(pb + (size_t)16 * K + k0,       &Bs[0][w * 32 + 16][0]);
            gload_lds16(pb + k0 + 32,                   &Bs[1][w * 32][0]);
            gload_lds16(pb + (size_t)16 * K + k0 + 32,  &Bs[1][w * 32 + 16][0]);
        } else {
            gload_lds16(pb + k0,                        &Bs[0][w * 16][0]);
            gload_lds16(pb + k0 + 32,                   &Bs[1][w * 16][0]);
        }
        __syncthreads();
#pragma unroll
        for (int p = 0; p < 2; ++p) {
            short8 af[4], bfv[NFRAG];
#pragma unroll
            for (int f = 0; f < 4; ++f)
                af[f] = *(const short8*)&As[p][wm + f * 16 + lr][lg * 8];
#pragma unroll
            for (int f = 0; f < NFRAG; ++f)
                bfv[f] = *(const short8*)&Bs[p][wn + f * 16 + lr][lg * 8];
#pragma unroll
            for (int mf = 0; mf < 4; ++mf)
#pragma unroll
                for (int nf = 0; nf < NFRAG; ++nf)
                    acc[mf][nf] = __builtin_amdgcn_mfma_f32_16x16x32_bf16(af[mf], bfv[nf], acc[mf][nf], 0, 0, 0);
        }
    }

#pragma unroll
    for (int mf = 0; mf < 4; ++mf)
#pragma unroll
        for (int nf = 0; nf < NFRAG; ++nf) {
            int n = n0 + wn + nf * 16 + lr;
            int mbase = m0 + wm + mf * 16 + lg * 4;
            float bv = bias[n];
            if (VSPLIT && n >= 1536) {
                int hh = (n - 1536) >> 6, dd = (n - 1536) & 63;
                int bb = mbase >> 10, tt = mbase & 1023;
                ushort4 o;
                o.x = f2bf(acc[mf][nf][0] + bv);
                o.y = f2bf(acc[mf][nf][1] + bv);
                o.z = f2bf(acc[mf][nf][2] + bv);
                o.w = f2bf(acc[mf][nf][3] + bv);
                *(ushort4*)&Vt[(((size_t)bb * 12 + hh) * 64 + dd) * 1024 + tt] = o;
            } else {
#pragma unroll
                for (int r = 0; r < 4; ++r) {
                    float v = acc[mf][nf][r] + bv;
                    if (F32OUT) ((float*)Cout)[(size_t)(mbase + r) * N + n] = v;
                    else ((unsigned short*)Cout)[(size_t)(mbase + r) * N + n] = f2bf(v);
                }
            }
        }
}

// ---------------- causal flash attention: swapped-QK^T, SINGLE-buffered K/V ----------------
// R14 inner math + mapping frozen. R18: drop the K/V double buffer -> LDS 54.3->31.7KB
// -> 5 blocks/CU (20 waves, was 3/12). Attn is latency-bound (MfmaUtil 12%, VALUBusy 22%,
// Occ 26%); more co-resident waves hide the serial QK->softmax->PV chain. Async-split
// staging kept: loads for t+1 issued into REGS before compute of t (T14), written to LDS
// after the post-compute barrier. 2 barriers/tile (write-after-read, read-after-write);
// independent blocks interleave across the extra barrier.
__global__ __launch_bounds__(256, 3)
void k_attn(const unsigned short* __restrict__ qkv, const unsigned short* __restrict__ vt,
            unsigned short* __restrict__ y) {
    __shared__ unsigned short Ks[64][88];
    __shared__ unsigned short Vs[64][88];
    __shared__ unsigned short Ps[4][16][72];
    const int p = blockIdx.x;
    const int s = p >> 3;                        // slot within XCD (0..95)
    const int bh = (p & 7) * 12 + (s >> 3);
    const int qt = 7 - ((s + 3 * (s >> 5)) & 7); // R14 stagger (measured best)
    const int b = bh / 12, h = bh % 12;
    const int t = threadIdx.x, w = t >> 6, l = t & 63, lr = l & 15, lg = l >> 4;
    const int q0 = qt * 128;

    const unsigned short* qbase = qkv + (size_t)b * 1024 * 2304 + h * 64;
    const unsigned short* kbase = qbase + 768;
    const unsigned short* vbase = vt + (size_t)bh * 64 * 1024;

    const int srow = t >> 2, scol = (t & 3) * 8;
    const unsigned short* kst = &kbase[(size_t)srow * 2304 + scol];
    const unsigned short* vst = &vbase[(size_t)srow * 1024 + scol];

    short8 qf[2][2];
#pragma unroll
    for (int g = 0; g < 2; ++g) {
        const unsigned short* qrow = &qbase[(size_t)(q0 + g * 64 + w * 16 + lr) * 2304];
        qf[g][0] = *(const short8*)&qrow[lg * 8];
        qf[g][1] = *(const short8*)&qrow[32 + lg * 8];
    }

    float l_loc[2] = {0.0f, 0.0f};
    f32x4 o_acc[2][4];
#pragma unroll
    for (int g = 0; g < 2; ++g)
#pragma unroll
        for (int df = 0; df < 4; ++df)
#pragma unroll
            for (int r = 0; r < 4; ++r) o_acc[g][df][r] = 0.0f;

    // prologue: stage tile 0
    {
        uint4 ka = *(const uint4*)(kst);
        uint4 kb = *(const uint4*)(kst + 32);
        uint4 va = *(const uint4*)(vst);
        uint4 vb = *(const uint4*)(vst + 32);
        *(uint4*)&Ks[srow][scol]      = ka;
        *(uint4*)&Ks[srow][scol + 32] = kb;
        *(uint4*)&Vs[srow][scol]      = va;
        *(uint4*)&Vs[srow][scol + 32] = vb;
    }
    __syncthreads();

    const int nkt = qt * 2 + 2;
    for (int kti = 0; kti < nkt; ++kti) {
        const int kt = kti * 64;
        const bool more = (kti + 1 < nkt);
        // async-split: issue next tile's loads NOW; latency hides under compute
        uint4 nka, nkb, nva, nvb;
        if (more) {
            const int kn = kt + 64;
            nka = *(const uint4*)(kst + (size_t)kn * 2304);
            nkb = *(const uint4*)(kst + (size_t)kn * 2304 + 32);
            nva = *(const uint4*)(vst + kn);
            nvb = *(const uint4*)(vst + kn + 32);
        }

        const bool act0 = (kti < nkt - 1);
        const bool dg0  = (kti == nkt - 2);
        const bool dg1  = (kti == nkt - 1);

        f32x4 s0[4], s1[4];
        __builtin_amdgcn_s_setprio(1);
#pragma unroll
        for (int nf = 0; nf < 4; ++nf) {
            short8 kf0 = *(const short8*)&Ks[nf * 16 + lr][lg * 8];
            short8 kf1 = *(const short8*)&Ks[nf * 16 + lr][32 + lg * 8];
            f32x4 z0, z1;
#pragma unroll
            for (int r = 0; r < 4; ++r) { z0[r] = 0.0f; z1[r] = 0.0f; }
            if (act0 && (!dg0 || nf <= w)) {
                z0 = __builtin_amdgcn_mfma_f32_16x16x32_bf16(kf0, qf[0][0], z0, 0, 0, 0);
                z0 = __builtin_amdgcn_mfma_f32_16x16x32_bf16(kf1, qf[0][1], z0, 0, 0, 0);
            }
            if (!dg1 || nf <= w) {
                z1 = __builtin_amdgcn_mfma_f32_16x16x32_bf16(kf0, qf[1][0], z1, 0, 0, 0);
                z1 = __builtin_amdgcn_mfma_f32_16x16x32_bf16(kf1, qf[1][1], z1, 0, 0, 0);
            }
            s0[nf] = z0; s1[nf] = z1;
        }
        __builtin_amdgcn_s_setprio(0);

        // V fragments: g-invariant, read once per tile
        short8 vf[4][2];
#pragma unroll
        for (int df = 0; df < 4; ++df) {
            vf[df][0] = *(const short8*)&Vs[df * 16 + lr][lg * 8];
            vf[df][1] = *(const short8*)&Vs[df * 16 + lr][32 + lg * 8];
        }

#pragma unroll
        for (int g = 0; g < 2; ++g) {
            if (g == 0 && !act0) continue;
            const bool diag = g ? dg1 : dg0;
            const int row = q0 + g * 64 + w * 16 + lr;
            float lsum = 0.0f;
#pragma unroll
            for (int nf = 0; nf < 4; ++nf) {
                float e[4];
#pragma unroll
                for (int r = 0; r < 4; ++r) {
                    int col = kt + nf * 16 + lg * 4 + r;
                    bool ok = !diag || (nf < w) || (col <= row);
                    float sv = g ? s1[nf][r] : s0[nf][r];
                    e[r] = ok ? __builtin_amdgcn_exp2f(fmaf(sv, 0.18033688f, -11.54156003f)) : 0.0f;
                    lsum += e[r];
                }
                uint2 u;
                u.x = cvtpk(e[0], e[1]);
                u.y = cvtpk(e[2], e[3]);
                *(uint2*)&Ps[w][lr][nf * 16 + lg * 4] = u;
            }
            l_loc[g] += lsum;
            short8 pf0 = *(const short8*)&Ps[w][lr][lg * 8];
            short8 pf1 = *(const short8*)&Ps[w][lr][32 + lg * 8];
            __builtin_amdgcn_s_setprio(1);
#pragma unroll
            for (int df = 0; df < 4; ++df) {
                o_acc[g][df] = __builtin_amdgcn_mfma_f32_16x16x32_bf16(pf0, vf[df][0], o_acc[g][df], 0, 0, 0);
                o_acc[g][df] = __builtin_amdgcn_mfma_f32_16x16x32_bf16(pf1, vf[df][1], o_acc[g][df], 0, 0, 0);
            }
            __builtin_amdgcn_s_setprio(0);
        }

        if (more) {
            __syncthreads();   // all waves done READING tile kti
            *(uint4*)&Ks[srow][scol]      = nka;
            *(uint4*)&Ks[srow][scol + 32] = nkb;
            *(uint4*)&Vs[srow][scol]      = nva;
            *(uint4*)&Vs[srow][scol + 32] = nvb;
            __syncthreads();   // tile kti+1 visible to all
        }
    }

#pragma unroll
    for (int g = 0; g < 2; ++g) {
        float dsum = l_loc[g];
        dsum += __shfl_xor(dsum, 16);
        dsum += __shfl_xor(dsum, 32);
#pragma unroll
        for (int r = 0; r < 4; ++r) {
            float inv = 1.0f / __shfl(dsum, lg * 4 + r);
            int rowy = q0 + g * 64 + w * 16 + lg * 4 + r;
#pragma unroll
            for (int df = 0; df < 4; ++df)
                y[((size_t)b * 1024 + rowy) * 768 + h * 64 + df * 16 + lr] = f2bf(o_acc[g][df][r] * inv);
        }
    }
}

extern "C" void kernel_launch(void* const* d_in, const int* in_sizes, int n_in,
                              void* d_out, int out_size, void* d_ws, size_t ws_size,
                              hipStream_t stream) {
    const float* x  = (const float*)d_in[0];
    const float* Wa = (const float*)d_in[1];
    const float* ba = (const float*)d_in[2];
    const float* Wp = (const float*)d_in[3];
    const float* bp = (const float*)d_in[4];
    float* out = (float*)d_out;

    char* ws = (char*)d_ws;
    unsigned short* qkv = (unsigned short*)ws;                          // 8192*2304*2 = 37,748,736
    unsigned short* xb  = (unsigned short*)(ws + 37748736);             // 8192*768*2  = 12,582,912
    unsigned short* WaT = (unsigned short*)(ws + 37748736 + 12582912);  // 2304*768*2  =  3,538,944
    unsigned short* WpT = (unsigned short*)(ws + 37748736 + 12582912 + 3538944); // 768*768*2
    unsigned short* y   = xb;    // reuse: xb dead after gemm1
    unsigned short* vtb = (unsigned short*)d_out;  // V^T scratch in d_out, overwritten by gemm2

    // 1) fused prep: x->bf16, W_attn transpose, W_proj transpose
    k_prep<<<8448, 256, 0, stream>>>(x, xb, Wa, WaT, Wp, WpT);
    // 2) qkv = xb @ WaT^T + b_attn (bf16); V heads written transposed straight to vtb
    k_gemm_bt<false, true, 4><<<dim3(18, 64), 256, 0, stream>>>(xb, WaT, ba, qkv, vtb, 8192, 2304, 768);
    // 3) causal flash attention -> y (bf16)
    k_attn<<<768, 256, 0, stream>>>(qkv, vtb, y);
    // 4) out = y @ WpT^T + b_proj (fp32); 128x64 tiles -> 768 blocks = 3.0/CU exact
    k_gemm_bt<true, false, 2><<<dim3(12, 64), 256, 0, stream>>>(y, WpT, bp, out, nullptr, 8192, 768, 768);
}